// Round 6
// baseline (281.886 us; speedup 1.0000x reference)
//
#include <hip/hip_runtime.h>

// ---- problem constants -----------------------------------------------------
#define IN_DIM   1024
#define OUT_DIM  1024
#define BATCH    4096
#define NC       8        // N_COEFFS
#define NK       12       // N_KNOTS
#define KSPLINE  (IN_DIM * NC)      // 8192
#define KDIM     (KSPLINE + IN_DIM) // 9216
#define EPS      1e-8f
#define KSPLIT   8
#define KT_PER   (KDIM / 64 / KSPLIT)  // 18 k-iterations per split block

typedef _Float16 f16x8 __attribute__((ext_vector_type(8)));
typedef float    f32x4 __attribute__((ext_vector_type(4)));

static __device__ __forceinline__ unsigned short f2h_bits(float f) {
  _Float16 h = (_Float16)f;
  return __builtin_bit_cast(unsigned short, h);
}

// async 16B/lane global->LDS copy; LDS dest is wave-uniform base + lane*16
static __device__ __forceinline__ void gl_lds16(const unsigned short* g, unsigned short* l) {
  __builtin_amdgcn_global_load_lds(
      (const __attribute__((address_space(1))) unsigned int*)g,
      (__attribute__((address_space(3))) unsigned int*)l, 16, 0, 0);
}

// ---- kernel 1: TRANSPOSED grid rows + reciprocal tables --------------------
__global__ void build_grid_k(const float* __restrict__ gsl,
                             const float* __restrict__ gstart,
                             float* __restrict__ gT,
                             float* __restrict__ rT) {
  int i = blockIdx.x * 256 + threadIdx.x;
  if (i >= IN_DIM) return;
  float g[NK];
  float acc = gstart[i];
  g[0] = acc;
#pragma unroll
  for (int t = 0; t < NK - 1; ++t) {
    float v  = gsl[i * (NK - 1) + t];
    float sp = (v > 20.f) ? v : log1pf(expf(v));  // softplus
    acc += sp;
    g[t + 1] = acc;
  }
#pragma unroll
  for (int t = 0; t < NK; ++t) gT[t * IN_DIM + i] = g[t];
#pragma unroll
  for (int j = 0; j < 11; ++j) rT[(j)      * IN_DIM + i] = 1.f / (g[j + 1] - g[j] + EPS);
#pragma unroll
  for (int j = 0; j < 10; ++j) rT[(11 + j) * IN_DIM + i] = 1.f / (g[j + 2] - g[j] + EPS);
#pragma unroll
  for (int j = 0; j <  9; ++j) rT[(21 + j) * IN_DIM + i] = 1.f / (g[j + 3] - g[j] + EPS);
}

// ---- kernel 2: A[b, i*8..+7] = cubic B-spline basis; A[b, 8192+i] = silu ---
// Also fuses out[b,i] = res_scale * x[b,i] (the gemm atomics accumulate on top).
__global__ __launch_bounds__(256, 2) void build_A_k(const float* __restrict__ x,
                                                    const float* __restrict__ gT,
                                                    const float* __restrict__ rT,
                                                    const float* __restrict__ rsp,
                                                    unsigned short* __restrict__ A,
                                                    float* __restrict__ out) {
  const int i  = (blockIdx.x & 3) * 256 + threadIdx.x;
  const int b0 = (blockIdx.x >> 2) * 16;
  const float rs = rsp[0];
  float g[NK], r[30];
#pragma unroll
  for (int t = 0; t < NK; ++t) g[t] = gT[t * IN_DIM + i];   // coalesced
#pragma unroll
  for (int t = 0; t < 30; ++t) r[t] = rT[t * IN_DIM + i];   // coalesced

  for (int bb = 0; bb < 16; ++bb) {
    const int b = b0 + bb;
    float xv = x[(size_t)b * IN_DIM + i];
    float bas[NK - 1];
#pragma unroll
    for (int k = 0; k < NK - 1; ++k)
      bas[k] = (xv >= g[k] && xv < g[k + 1]) ? 1.f : 0.f;
    const int off[3] = {0, 11, 21};
#pragma unroll
    for (int d = 1; d <= 3; ++d) {
#pragma unroll
      for (int k = 0; k < NK - 1 - d; ++k) {
        float left  = (xv - g[k])         * r[off[d - 1] + k];
        float right = (g[k + d + 1] - xv) * r[off[d - 1] + k + 1];
        bas[k] = left * bas[k] + right * bas[k + 1];
      }
    }
    uint4 pack;
    pack.x = (unsigned)f2h_bits(bas[0]) | ((unsigned)f2h_bits(bas[1]) << 16);
    pack.y = (unsigned)f2h_bits(bas[2]) | ((unsigned)f2h_bits(bas[3]) << 16);
    pack.z = (unsigned)f2h_bits(bas[4]) | ((unsigned)f2h_bits(bas[5]) << 16);
    pack.w = (unsigned)f2h_bits(bas[6]) | ((unsigned)f2h_bits(bas[7]) << 16);
    *(uint4*)&A[(size_t)b * KDIM + i * NC] = pack;
    float s = xv / (1.f + expf(-xv));  // silu
    A[(size_t)b * KDIM + KSPLINE + i] = f2h_bits(s);
    out[(size_t)b * OUT_DIM + i] = rs * xv;  // fused init_out
  }
}

// ---- kernel 3: W[n, :8192]=f16(coeffs[n,:]), W[n, 8192:]=f16(bw[n,:]) ------
__global__ void build_W_k(const float* __restrict__ coeffs,
                          const float* __restrict__ bw,
                          unsigned short* __restrict__ W) {
  int idx = blockIdx.x * 256 + threadIdx.x;   // over 1024 * (9216/4)
  int n  = idx / (KDIM / 4);
  int k4 = (idx - n * (KDIM / 4)) * 4;
  float4 v;
  if (k4 < KSPLINE) v = *(const float4*)&coeffs[(size_t)n * KSPLINE + k4];
  else              v = *(const float4*)&bw[(size_t)n * IN_DIM + (k4 - KSPLINE)];
  ushort4 o;
  o.x = f2h_bits(v.x); o.y = f2h_bits(v.y); o.z = f2h_bits(v.z); o.w = f2h_bits(v.w);
  *(ushort4*)&W[(size_t)n * KDIM + k4] = o;
}

// ---- kernel 4: out += A @ W^T (f16 MFMA), K-split x8, atomic epilogue ------
// 128x128 tile, BK=64, 256 threads (4 waves), 2048 blocks -> 5 resident
// blocks/CU (LDS 160/32) so independent blocks cover each other's barrier
// vmcnt(0) drains (m114); K-loop is 18 barrier-pairs per block.
__global__ __launch_bounds__(256) void gemm_k(const unsigned short* __restrict__ A,
                                              const unsigned short* __restrict__ W,
                                              float* __restrict__ out) {
  __shared__ __align__(16) unsigned short As[128 * 64];  // 16 KB
  __shared__ __align__(16) unsigned short Bs[128 * 64];  // 16 KB
  const int tid  = threadIdx.x;
  const int wave = tid >> 6;
  const int lane = tid & 63;
  const int ks = blockIdx.x >> 8;        // K-split slice 0..7
  const int t  = blockIdx.x & 255;
  const int bm = t & 31;                 // same-bm blocks stride 32 -> same XCD
  const int bn = t >> 5;
  const int l3 = lane >> 3;              // row-within-8 for staging
  const int l7 = lane & 7;               // 16B chunk for staging
  const int colsw = (l7 ^ l3) * 8;       // XOR-swizzled k-offset (elements)
  const unsigned short* aG = A + (size_t)(bm * 128 + wave * 8 + l3) * KDIM + colsw
                               + (size_t)ks * (KT_PER * 64);
  const unsigned short* bG = W + (size_t)(bn * 128 + wave * 8 + l3) * KDIM + colsw
                               + (size_t)ks * (KT_PER * 64);

  f32x4 acc[4][4] = {};
  const int quad = lane >> 4;
  const int r16  = lane & 15;
  const int wm   = (wave >> 1) * 64;
  const int wn   = (wave & 1) * 64;

  for (int kt = 0; kt < KT_PER; ++kt) {
    __syncthreads();  // prev compute done before overwriting LDS
#pragma unroll
    for (int j = 0; j < 4; ++j) {
      gl_lds16(aG + (size_t)j * 32 * KDIM, &As[(j * 4 + wave) * 512]);
      gl_lds16(bG + (size_t)j * 32 * KDIM, &Bs[(j * 4 + wave) * 512]);
    }
    __syncthreads();  // vmcnt(0) drain -> LDS tiles ready
#pragma unroll
    for (int kk = 0; kk < 2; ++kk) {
      f16x8 af[4], bf[4];
#pragma unroll
      for (int mt = 0; mt < 4; ++mt) {
        int row = wm + mt * 16 + r16;
        int col = (kk * 32 + quad * 8) ^ ((row & 7) * 8);
        af[mt] = *(const f16x8*)&As[row * 64 + col];
      }
#pragma unroll
      for (int nt = 0; nt < 4; ++nt) {
        int row = wn + nt * 16 + r16;
        int col = (kk * 32 + quad * 8) ^ ((row & 7) * 8);
        bf[nt] = *(const f16x8*)&Bs[row * 64 + col];
      }
#pragma unroll
      for (int mt = 0; mt < 4; ++mt)
#pragma unroll
        for (int nt = 0; nt < 4; ++nt)
          acc[mt][nt] = __builtin_amdgcn_mfma_f32_16x16x32_f16(af[mt], bf[nt], acc[mt][nt], 0, 0, 0);
    }
    aG += 64;
    bG += 64;
  }

  // epilogue: C/D layout col = lane&15, row = quad*4 + r; atomic K-split sum
#pragma unroll
  for (int mt = 0; mt < 4; ++mt) {
#pragma unroll
    for (int r = 0; r < 4; ++r) {
      int row = bm * 128 + wm + mt * 16 + quad * 4 + r;
      float* orow = out + (size_t)row * OUT_DIM;
#pragma unroll
      for (int nt = 0; nt < 4; ++nt) {
        int col = bn * 128 + wn + nt * 16 + r16;
        atomicAdd(&orow[col], acc[mt][nt][r]);
      }
    }
  }
}

// ---- host-side launch ------------------------------------------------------
extern "C" void kernel_launch(void* const* d_in, const int* in_sizes, int n_in,
                              void* d_out, int out_size, void* d_ws, size_t ws_size,
                              hipStream_t stream) {
  const float* x      = (const float*)d_in[0];  // (4096, 1024) fp32
  const float* coeffs = (const float*)d_in[1];  // (1024, 8192)
  const float* bw     = (const float*)d_in[2];  // (1024, 1024)
  const float* gsl    = (const float*)d_in[3];  // (1024, 11)
  const float* gstart = (const float*)d_in[4];  // (1024, 1)
  const float* rsp    = (const float*)d_in[5];  // (1,)

  // ws layout: A (75.5 MB f16) | W (18.9 MB f16). Transposed tables (168 KB)
  // live at the head of the W region: build_grid writes, build_A consumes,
  // THEN build_W overwrites (stream order guarantees safety).
  char* ws = (char*)d_ws;
  unsigned short* A  = (unsigned short*)ws;
  unsigned short* W  = (unsigned short*)(ws + (size_t)BATCH * KDIM * 2);
  float*          gT = (float*)W;                  // 12*1024 floats
  float*          rT = gT + 12 * IN_DIM;           // 30*1024 floats
  float*          out = (float*)d_out;

  build_grid_k<<<4, 256, 0, stream>>>(gsl, gstart, gT, rT);
  build_A_k<<<(IN_DIM / 256) * (BATCH / 16), 256, 0, stream>>>(x, gT, rT, rsp, A, out);
  build_W_k<<<(OUT_DIM * (KDIM / 4)) / 256, 256, 0, stream>>>(coeffs, bw, W);
  gemm_k<<<256 * KSPLIT, 256, 0, stream>>>(A, W, out);
}

// Round 7
// 253.680 us; speedup vs baseline: 1.1112x; 1.1112x over previous
//
#include <hip/hip_runtime.h>

// ---- problem constants -----------------------------------------------------
#define IN_DIM   1024
#define OUT_DIM  1024
#define BATCH    4096
#define NC       8        // N_COEFFS
#define NK       12       // N_KNOTS
#define KSPLINE  (IN_DIM * NC)      // 8192
#define KDIM     (KSPLINE + IN_DIM) // 9216
#define EPS      1e-8f
#define KSPLIT   4
#define KT_PER   (KDIM / 64 / KSPLIT)  // 36 k-iterations per split block

#define NBLK_A   ((IN_DIM / 256) * (BATCH / 16))      // 1024 A-builder blocks
#define NBLK_W   ((OUT_DIM * (KDIM / 4)) / 256)       // 9216 W-builder blocks

typedef _Float16 f16x8 __attribute__((ext_vector_type(8)));
typedef float    f32x4 __attribute__((ext_vector_type(4)));

static __device__ __forceinline__ unsigned short f2h_bits(float f) {
  _Float16 h = (_Float16)f;
  return __builtin_bit_cast(unsigned short, h);
}

// async 16B/lane global->LDS copy; LDS dest is wave-uniform base + lane*16
static __device__ __forceinline__ void gl_lds16(const unsigned short* g, unsigned short* l) {
  __builtin_amdgcn_global_load_lds(
      (const __attribute__((address_space(1))) unsigned int*)g,
      (__attribute__((address_space(3))) unsigned int*)l, 16, 0, 0);
}

// ---- kernel 1: fused prep --------------------------------------------------
// blocks [0, NBLK_A):            A[b, i*8..+7] = cubic B-spline basis,
//                                A[b, 8192+i] = silu(x), out[b,i] = rs*x[b,i].
//                                Tables (grid knots + reciprocals) computed
//                                per-thread from gsl/gstart (L2-resident 48KB,
//                                redundant compute is ~1.4 us of VALU — cheaper
//                                than a separate kernel + global round-trip).
// blocks [NBLK_A, NBLK_A+NBLK_W): W[n,:8192]=f16(coeffs), W[n,8192:]=f16(bw).
// The two paths are independent -> they overlap instead of serializing.
__global__ __launch_bounds__(256) void prep_k(const float* __restrict__ x,
                                              const float* __restrict__ coeffs,
                                              const float* __restrict__ bw,
                                              const float* __restrict__ gsl,
                                              const float* __restrict__ gstart,
                                              const float* __restrict__ rsp,
                                              unsigned short* __restrict__ A,
                                              unsigned short* __restrict__ W,
                                              float* __restrict__ out) {
  const int blk = blockIdx.x;
  if (blk < NBLK_A) {
    // ---- A path ----
    const int i  = (blk & 3) * 256 + threadIdx.x;
    const int b0 = (blk >> 2) * 16;
    const float rs = rsp[0];
    // knot vector for this input dim
    float g[NK];
    float acc = gstart[i];
    g[0] = acc;
#pragma unroll
    for (int t = 0; t < NK - 1; ++t) {
      float v  = gsl[i * (NK - 1) + t];
      float sp = (v > 20.f) ? v : log1pf(expf(v));  // softplus
      acc += sp;
      g[t + 1] = acc;
    }
    // reciprocal tables (one divide set per thread, amortized over 16 b rows)
    float r[30];
#pragma unroll
    for (int j = 0; j < 11; ++j) r[j]      = 1.f / (g[j + 1] - g[j] + EPS);
#pragma unroll
    for (int j = 0; j < 10; ++j) r[11 + j] = 1.f / (g[j + 2] - g[j] + EPS);
#pragma unroll
    for (int j = 0; j <  9; ++j) r[21 + j] = 1.f / (g[j + 3] - g[j] + EPS);

    for (int bb = 0; bb < 16; ++bb) {
      const int b = b0 + bb;
      float xv = x[(size_t)b * IN_DIM + i];
      float bas[NK - 1];
#pragma unroll
      for (int k = 0; k < NK - 1; ++k)
        bas[k] = (xv >= g[k] && xv < g[k + 1]) ? 1.f : 0.f;
      const int off[3] = {0, 11, 21};
#pragma unroll
      for (int d = 1; d <= 3; ++d) {
#pragma unroll
        for (int k = 0; k < NK - 1 - d; ++k) {
          float left  = (xv - g[k])         * r[off[d - 1] + k];
          float right = (g[k + d + 1] - xv) * r[off[d - 1] + k + 1];
          bas[k] = left * bas[k] + right * bas[k + 1];
        }
      }
      uint4 pack;
      pack.x = (unsigned)f2h_bits(bas[0]) | ((unsigned)f2h_bits(bas[1]) << 16);
      pack.y = (unsigned)f2h_bits(bas[2]) | ((unsigned)f2h_bits(bas[3]) << 16);
      pack.z = (unsigned)f2h_bits(bas[4]) | ((unsigned)f2h_bits(bas[5]) << 16);
      pack.w = (unsigned)f2h_bits(bas[6]) | ((unsigned)f2h_bits(bas[7]) << 16);
      *(uint4*)&A[(size_t)b * KDIM + i * NC] = pack;
      float s = xv / (1.f + expf(-xv));  // silu
      A[(size_t)b * KDIM + KSPLINE + i] = f2h_bits(s);
      out[(size_t)b * OUT_DIM + i] = rs * xv;  // init for gemm's atomic sum
    }
  } else {
    // ---- W path ----
    int idx = (blk - NBLK_A) * 256 + threadIdx.x;   // over 1024 * (9216/4)
    int n  = idx / (KDIM / 4);
    int k4 = (idx - n * (KDIM / 4)) * 4;
    float4 v;
    if (k4 < KSPLINE) v = *(const float4*)&coeffs[(size_t)n * KSPLINE + k4];
    else              v = *(const float4*)&bw[(size_t)n * IN_DIM + (k4 - KSPLINE)];
    ushort4 o;
    o.x = f2h_bits(v.x); o.y = f2h_bits(v.y); o.z = f2h_bits(v.z); o.w = f2h_bits(v.w);
    *(ushort4*)&W[(size_t)n * KDIM + k4] = o;
  }
}

// ---- kernel 2: out += A @ W^T (f16 MFMA), K-split x4, atomic epilogue ------
// 128x128 tile, BK=64, 256 threads (4 waves), 1024 blocks -> 4 blocks/CU.
// KSPLIT=4 is the sweet spot: KSPLIT=8 regressed (atomic serialization,
// R6: 146us vs 122us despite higher occupancy).
__global__ __launch_bounds__(256) void gemm_k(const unsigned short* __restrict__ A,
                                              const unsigned short* __restrict__ W,
                                              float* __restrict__ out) {
  __shared__ __align__(16) unsigned short As[128 * 64];  // 16 KB
  __shared__ __align__(16) unsigned short Bs[128 * 64];  // 16 KB
  const int tid  = threadIdx.x;
  const int wave = tid >> 6;
  const int lane = tid & 63;
  const int ks = blockIdx.x >> 8;        // K-split slice 0..3
  const int t  = blockIdx.x & 255;
  const int bm = t & 31;                 // same-bm blocks stride 32 -> same XCD
  const int bn = t >> 5;
  const int l3 = lane >> 3;              // row-within-8 for staging
  const int l7 = lane & 7;               // 16B chunk for staging
  const int colsw = (l7 ^ l3) * 8;       // XOR-swizzled k-offset (elements)
  const unsigned short* aG = A + (size_t)(bm * 128 + wave * 8 + l3) * KDIM + colsw
                               + (size_t)ks * (KT_PER * 64);
  const unsigned short* bG = W + (size_t)(bn * 128 + wave * 8 + l3) * KDIM + colsw
                               + (size_t)ks * (KT_PER * 64);

  f32x4 acc[4][4] = {};
  const int quad = lane >> 4;
  const int r16  = lane & 15;
  const int wm   = (wave >> 1) * 64;
  const int wn   = (wave & 1) * 64;

  for (int kt = 0; kt < KT_PER; ++kt) {
    __syncthreads();  // prev compute done before overwriting LDS
#pragma unroll
    for (int j = 0; j < 4; ++j) {
      gl_lds16(aG + (size_t)j * 32 * KDIM, &As[(j * 4 + wave) * 512]);
      gl_lds16(bG + (size_t)j * 32 * KDIM, &Bs[(j * 4 + wave) * 512]);
    }
    __syncthreads();  // vmcnt(0) drain -> LDS tiles ready
#pragma unroll
    for (int kk = 0; kk < 2; ++kk) {
      f16x8 af[4], bf[4];
#pragma unroll
      for (int mt = 0; mt < 4; ++mt) {
        int row = wm + mt * 16 + r16;
        int col = (kk * 32 + quad * 8) ^ ((row & 7) * 8);
        af[mt] = *(const f16x8*)&As[row * 64 + col];
      }
#pragma unroll
      for (int nt = 0; nt < 4; ++nt) {
        int row = wn + nt * 16 + r16;
        int col = (kk * 32 + quad * 8) ^ ((row & 7) * 8);
        bf[nt] = *(const f16x8*)&Bs[row * 64 + col];
      }
#pragma unroll
      for (int mt = 0; mt < 4; ++mt)
#pragma unroll
        for (int nt = 0; nt < 4; ++nt)
          acc[mt][nt] = __builtin_amdgcn_mfma_f32_16x16x32_f16(af[mt], bf[nt], acc[mt][nt], 0, 0, 0);
    }
    aG += 64;
    bG += 64;
  }

  // epilogue: C/D layout col = lane&15, row = quad*4 + r; atomic K-split sum
#pragma unroll
  for (int mt = 0; mt < 4; ++mt) {
#pragma unroll
    for (int r = 0; r < 4; ++r) {
      int row = bm * 128 + wm + mt * 16 + quad * 4 + r;
      float* orow = out + (size_t)row * OUT_DIM;
#pragma unroll
      for (int nt = 0; nt < 4; ++nt) {
        int col = bn * 128 + wn + nt * 16 + r16;
        atomicAdd(&orow[col], acc[mt][nt][r]);
      }
    }
  }
}

// ---- host-side launch ------------------------------------------------------
extern "C" void kernel_launch(void* const* d_in, const int* in_sizes, int n_in,
                              void* d_out, int out_size, void* d_ws, size_t ws_size,
                              hipStream_t stream) {
  const float* x      = (const float*)d_in[0];  // (4096, 1024) fp32
  const float* coeffs = (const float*)d_in[1];  // (1024, 8192)
  const float* bw     = (const float*)d_in[2];  // (1024, 1024)
  const float* gsl    = (const float*)d_in[3];  // (1024, 11)
  const float* gstart = (const float*)d_in[4];  // (1024, 1)
  const float* rsp    = (const float*)d_in[5];  // (1,)

  // ws layout: A (75.5 MB f16) | W (18.9 MB f16) = 94.4 MB total (proven fit)
  char* ws = (char*)d_ws;
  unsigned short* A  = (unsigned short*)ws;
  unsigned short* W  = (unsigned short*)(ws + (size_t)BATCH * KDIM * 2);
  float*          out = (float*)d_out;

  prep_k<<<NBLK_A + NBLK_W, 256, 0, stream>>>(x, coeffs, bw, gsl, gstart, rsp, A, W, out);
  gemm_k<<<256 * KSPLIT, 256, 0, stream>>>(A, W, out);
}

// Round 8
// 245.005 us; speedup vs baseline: 1.1505x; 1.0354x over previous
//
#include <hip/hip_runtime.h>

// ---- problem constants -----------------------------------------------------
#define IN_DIM   1024
#define OUT_DIM  1024
#define BATCH    4096
#define NC       8        // N_COEFFS
#define NK       12       // N_KNOTS
#define KSPLINE  (IN_DIM * NC)      // 8192
#define KDIM     (KSPLINE + IN_DIM) // 9216
#define EPS      1e-8f
#define KSPLIT   4
#define KT_PER   (KDIM / 64 / KSPLIT)  // 36 k-iterations per split block

#define NBLK_A   ((IN_DIM / 256) * (BATCH / 16))      // 1024 A-builder blocks
#define NBLK_W   ((OUT_DIM * (KDIM / 4)) / 256)       // 9216 W-builder blocks

typedef _Float16 f16x8  __attribute__((ext_vector_type(8)));
typedef float    f32x16 __attribute__((ext_vector_type(16)));

static __device__ __forceinline__ unsigned short f2h_bits(float f) {
  _Float16 h = (_Float16)f;
  return __builtin_bit_cast(unsigned short, h);
}

// async 16B/lane global->LDS copy; LDS dest is wave-uniform base + lane*16
static __device__ __forceinline__ void gl_lds16(const unsigned short* g, unsigned short* l) {
  __builtin_amdgcn_global_load_lds(
      (const __attribute__((address_space(1))) unsigned int*)g,
      (__attribute__((address_space(3))) unsigned int*)l, 16, 0, 0);
}

// ---- kernel 1: fused prep (A path + W path in one launch, overlapping) -----
__global__ __launch_bounds__(256) void prep_k(const float* __restrict__ x,
                                              const float* __restrict__ coeffs,
                                              const float* __restrict__ bw,
                                              const float* __restrict__ gsl,
                                              const float* __restrict__ gstart,
                                              const float* __restrict__ rsp,
                                              unsigned short* __restrict__ A,
                                              unsigned short* __restrict__ W,
                                              float* __restrict__ out) {
  const int blk = blockIdx.x;
  if (blk < NBLK_A) {
    // ---- A path: spline basis + silu + out = rs*x ----
    const int i  = (blk & 3) * 256 + threadIdx.x;
    const int b0 = (blk >> 2) * 16;
    const float rs = rsp[0];
    float g[NK];
    float acc = gstart[i];
    g[0] = acc;
#pragma unroll
    for (int t = 0; t < NK - 1; ++t) {
      float v  = gsl[i * (NK - 1) + t];
      float sp = (v > 20.f) ? v : log1pf(expf(v));  // softplus
      acc += sp;
      g[t + 1] = acc;
    }
    float r[30];
#pragma unroll
    for (int j = 0; j < 11; ++j) r[j]      = 1.f / (g[j + 1] - g[j] + EPS);
#pragma unroll
    for (int j = 0; j < 10; ++j) r[11 + j] = 1.f / (g[j + 2] - g[j] + EPS);
#pragma unroll
    for (int j = 0; j <  9; ++j) r[21 + j] = 1.f / (g[j + 3] - g[j] + EPS);

    for (int bb = 0; bb < 16; ++bb) {
      const int b = b0 + bb;
      float xv = x[(size_t)b * IN_DIM + i];
      float bas[NK - 1];
#pragma unroll
      for (int k = 0; k < NK - 1; ++k)
        bas[k] = (xv >= g[k] && xv < g[k + 1]) ? 1.f : 0.f;
      const int off[3] = {0, 11, 21};
#pragma unroll
      for (int d = 1; d <= 3; ++d) {
#pragma unroll
        for (int k = 0; k < NK - 1 - d; ++k) {
          float left  = (xv - g[k])         * r[off[d - 1] + k];
          float right = (g[k + d + 1] - xv) * r[off[d - 1] + k + 1];
          bas[k] = left * bas[k] + right * bas[k + 1];
        }
      }
      uint4 pack;
      pack.x = (unsigned)f2h_bits(bas[0]) | ((unsigned)f2h_bits(bas[1]) << 16);
      pack.y = (unsigned)f2h_bits(bas[2]) | ((unsigned)f2h_bits(bas[3]) << 16);
      pack.z = (unsigned)f2h_bits(bas[4]) | ((unsigned)f2h_bits(bas[5]) << 16);
      pack.w = (unsigned)f2h_bits(bas[6]) | ((unsigned)f2h_bits(bas[7]) << 16);
      *(uint4*)&A[(size_t)b * KDIM + i * NC] = pack;
      float s = xv / (1.f + expf(-xv));  // silu
      A[(size_t)b * KDIM + KSPLINE + i] = f2h_bits(s);
      out[(size_t)b * OUT_DIM + i] = rs * xv;  // init for gemm's atomic sum
    }
  } else {
    // ---- W path: f16 concat of coeffs | base_weight ----
    int idx = (blk - NBLK_A) * 256 + threadIdx.x;
    int n  = idx / (KDIM / 4);
    int k4 = (idx - n * (KDIM / 4)) * 4;
    float4 v;
    if (k4 < KSPLINE) v = *(const float4*)&coeffs[(size_t)n * KSPLINE + k4];
    else              v = *(const float4*)&bw[(size_t)n * IN_DIM + (k4 - KSPLINE)];
    ushort4 o;
    o.x = f2h_bits(v.x); o.y = f2h_bits(v.y); o.z = f2h_bits(v.z); o.w = f2h_bits(v.w);
    *(ushort4*)&W[(size_t)n * KDIM + k4] = o;
  }
}

// ---- kernel 2: out += A @ W^T via 32x32x16 f16 MFMA, K-split x4 ------------
// 128x128 tile, BK=64, 256 threads (4 waves), wave = 64x64 via 2x2 grid of
// 32x32x16 MFMAs (m119: 2495 TF ceiling vs 2176 for 16x16 — fewer issue
// slots, same staging). KSPLIT=4 proven sweet spot (R6: 8 regressed).
__global__ __launch_bounds__(256) void gemm_k(const unsigned short* __restrict__ A,
                                              const unsigned short* __restrict__ W,
                                              float* __restrict__ out) {
  __shared__ __align__(16) unsigned short As[128 * 64];  // 16 KB
  __shared__ __align__(16) unsigned short Bs[128 * 64];  // 16 KB
  const int tid  = threadIdx.x;
  const int wave = tid >> 6;
  const int lane = tid & 63;
  const int ks = blockIdx.x >> 8;        // K-split slice 0..3
  const int t  = blockIdx.x & 255;
  const int bm = t & 31;                 // same-bm blocks stride 32 -> same XCD
  const int bn = t >> 5;
  const int l3 = lane >> 3;              // row-within-8 for staging
  const int l7 = lane & 7;               // 16B chunk for staging
  const int colsw = (l7 ^ l3) * 8;       // XOR-swizzled k-offset (elements)
  const unsigned short* aG = A + (size_t)(bm * 128 + wave * 8 + l3) * KDIM + colsw
                               + (size_t)ks * (KT_PER * 64);
  const unsigned short* bG = W + (size_t)(bn * 128 + wave * 8 + l3) * KDIM + colsw
                               + (size_t)ks * (KT_PER * 64);

  f32x16 acc[2][2] = {};
  const int l31  = lane & 31;            // m/n within the 32x32 tile
  const int half = lane >> 5;            // k-half selector (operand layout)
  const int wm   = (wave >> 1) * 64;
  const int wn   = (wave & 1) * 64;

  for (int kt = 0; kt < KT_PER; ++kt) {
    __syncthreads();  // prev compute done before overwriting LDS
#pragma unroll
    for (int j = 0; j < 4; ++j) {
      gl_lds16(aG + (size_t)j * 32 * KDIM, &As[(j * 4 + wave) * 512]);
      gl_lds16(bG + (size_t)j * 32 * KDIM, &Bs[(j * 4 + wave) * 512]);
    }
    __syncthreads();  // vmcnt(0) drain -> LDS tiles ready
#pragma unroll
    for (int s = 0; s < 4; ++s) {        // four K=16 steps per BK=64
      f16x8 af[2], bf[2];
#pragma unroll
      for (int mt = 0; mt < 2; ++mt) {
        int row = wm + mt * 32 + l31;
        int col = (s * 16 + half * 8) ^ ((row & 7) * 8);
        af[mt] = *(const f16x8*)&As[row * 64 + col];
      }
#pragma unroll
      for (int nt = 0; nt < 2; ++nt) {
        int row = wn + nt * 32 + l31;
        int col = (s * 16 + half * 8) ^ ((row & 7) * 8);
        bf[nt] = *(const f16x8*)&Bs[row * 64 + col];
      }
#pragma unroll
      for (int mt = 0; mt < 2; ++mt)
#pragma unroll
        for (int nt = 0; nt < 2; ++nt)
          acc[mt][nt] = __builtin_amdgcn_mfma_f32_32x32x16_f16(af[mt], bf[nt], acc[mt][nt], 0, 0, 0);
    }
    aG += 64;
    bG += 64;
  }

  // epilogue: 32x32 C/D layout col=lane&31, row=(reg&3)+8*(reg>>2)+4*(lane>>5)
  // (m74/m101 HW-verified); atomic K-split accumulation
#pragma unroll
  for (int mt = 0; mt < 2; ++mt) {
#pragma unroll
    for (int reg = 0; reg < 16; ++reg) {
      int row = bm * 128 + wm + mt * 32 + (reg & 3) + 8 * (reg >> 2) + 4 * half;
      float* orow = out + (size_t)row * OUT_DIM;
#pragma unroll
      for (int nt = 0; nt < 2; ++nt) {
        int col = bn * 128 + wn + nt * 32 + l31;
        atomicAdd(&orow[col], acc[mt][nt][reg]);
      }
    }
  }
}

// ---- host-side launch ------------------------------------------------------
extern "C" void kernel_launch(void* const* d_in, const int* in_sizes, int n_in,
                              void* d_out, int out_size, void* d_ws, size_t ws_size,
                              hipStream_t stream) {
  const float* x      = (const float*)d_in[0];  // (4096, 1024) fp32
  const float* coeffs = (const float*)d_in[1];  // (1024, 8192)
  const float* bw     = (const float*)d_in[2];  // (1024, 1024)
  const float* gsl    = (const float*)d_in[3];  // (1024, 11)
  const float* gstart = (const float*)d_in[4];  // (1024, 1)
  const float* rsp    = (const float*)d_in[5];  // (1,)

  // ws layout: A (75.5 MB f16) | W (18.9 MB f16) = 94.4 MB total (proven fit)
  char* ws = (char*)d_ws;
  unsigned short* A  = (unsigned short*)ws;
  unsigned short* W  = (unsigned short*)(ws + (size_t)BATCH * KDIM * 2);
  float*          out = (float*)d_out;

  prep_k<<<NBLK_A + NBLK_W, 256, 0, stream>>>(x, coeffs, bw, gsl, gstart, rsp, A, W, out);
  gemm_k<<<256 * KSPLIT, 256, 0, stream>>>(A, W, out);
}